// Round 11
// baseline (813.159 us; speedup 1.0000x reference)
//
#include <hip/hip_runtime.h>
#include <hip/hip_bf16.h>

#define NN 50000
#define EE 800000
#define GG 512
#define HH 256
#define TT 32
#define LL 4
#define EPSF 1e-5f

typedef __attribute__((ext_vector_type(8))) short short8;
typedef __attribute__((ext_vector_type(4))) float float4v;

// ---------- bf16 helpers ----------
__device__ inline unsigned short f2b(float f) {  // RNE
    unsigned u = __float_as_uint(f);
    unsigned r = (u + 0x7FFFu + ((u >> 16) & 1u)) >> 16;
    return (unsigned short)r;
}
__device__ inline unsigned pack2(float lo, float hi) {  // v_cvt_pk_bf16_f32
    __hip_bfloat162 b2 = __float22bfloat162_rn(float2{lo, hi});
    return *reinterpret_cast<unsigned*>(&b2);
}
__device__ inline float4 bf4_to_f4(ushort4 u) {
    float4 f;
    f.x = __uint_as_float((unsigned)u.x << 16);
    f.y = __uint_as_float((unsigned)u.y << 16);
    f.z = __uint_as_float((unsigned)u.z << 16);
    f.w = __uint_as_float((unsigned)u.w << 16);
    return f;
}

// ---------------- degree ----------------
__global__ void k_degree(const int* __restrict__ dst, int* __restrict__ cnt, int E) {
    int e = blockIdx.x * 256 + threadIdx.x;
    if (e < E) atomicAdd(&cnt[dst[e]], 1);
}

// ---------------- scan phase 1: per-1024-chunk inclusive scan ----------------
__global__ void k_scan1(const int* __restrict__ cnt, int* __restrict__ incl,
                        int* __restrict__ bsum, int N) {
    __shared__ int s[1024];
    int i = blockIdx.x * 1024 + threadIdx.x;
    int v = (i < N) ? cnt[i] : 0;
    s[threadIdx.x] = v;
    __syncthreads();
    for (int off = 1; off < 1024; off <<= 1) {
        int t = (threadIdx.x >= off) ? s[threadIdx.x - off] : 0;
        __syncthreads();
        s[threadIdx.x] += t;
        __syncthreads();
    }
    if (i < N) incl[i] = s[threadIdx.x];
    if (threadIdx.x == 1023) bsum[blockIdx.x] = s[1023];
}

// ---------------- scan phase 2 (merged): local bsum scan + offsets + dinv + cur ----------------
// Each block redundantly exclusive-scans bsum[0..nb) (<=64 entries) in LDS, then
// finalizes rs (exclusive prefix), pre-inits cur = rs (so scatter needs no rs read),
// and computes dinv.
__global__ void k_scan3(int* __restrict__ rs, const int* __restrict__ cnt,
                        const int* __restrict__ bsum, int* __restrict__ cur,
                        float* __restrict__ dinv, int N, int nb) {
    __shared__ int sb[64];
    __shared__ int ex[64];
    int t = threadIdx.x;
    if (t < 64) sb[t] = (t < nb) ? bsum[t] : 0;
    __syncthreads();
    for (int off = 1; off < 64; off <<= 1) {
        int v = 0;
        if (t < 64 && t >= off) v = sb[t - off];
        __syncthreads();
        if (t < 64) sb[t] += v;
        __syncthreads();
    }
    if (t < 64) ex[t] = sb[t] - ((t < nb) ? bsum[t] : 0);  // exclusive
    __syncthreads();
    int i = blockIdx.x * 256 + t;
    if (i < N) {
        int c = cnt[i];
        int e = rs[i] + ex[i >> 10] - c;  // exclusive prefix
        rs[i] = e;
        cur[i] = e;
        dinv[i] = rsqrtf((float)c + 1.0f);
    }
}

// ---------------- merged prep: scatter | gbound | projw (independent jobs) ----------------
// grid = 3125 (scatter) + 196 (gbound) + 359 (projw: 256 wprep + 103 tables)
__global__ void k_prep(const int* __restrict__ src, const int* __restrict__ dst,
                       int* __restrict__ cur, int* __restrict__ csr,
                       const int* __restrict__ batch, int* __restrict__ gstart,
                       const float* __restrict__ atom_emb, const float* __restrict__ tag_emb,
                       const float* __restrict__ Wp, const float* __restrict__ bp,
                       const float* __restrict__ W,
                       float* __restrict__ aref, float* __restrict__ tref,
                       unsigned short* __restrict__ Wt) {
    int blk = blockIdx.x;
    if (blk < 3125) {  // scatter (cur pre-initialized to row starts)
        int e = blk * 256 + threadIdx.x;
        if (e >= EE) return;
        int p = atomicAdd(&cur[dst[e]], 1);
        csr[p] = src[e];
    } else if (blk < 3125 + 196) {  // gbound
        int n = (blk - 3125) * 256 + threadIdx.x;
        if (n >= NN) return;
        int b = batch[n];
        int prev = (n == 0) ? -1 : batch[n - 1];
        for (int g = prev + 1; g <= b; ++g) gstart[g] = n;
        if (n == NN - 1)
            for (int g = b + 1; g <= GG; ++g) gstart[g] = NN;
    } else {
        int pb = blk - 3321;  // 0..358
        if (pb < 256) {  // wprep: Wt[l][n][k] bf16
            int l = pb >> 6;
            int bx = pb & 63;
            int n = bx * 4 + (threadIdx.x >> 6);
            int kq = (threadIdx.x & 63) * 4;
            const float* Wl = W + (size_t)l * HH * HH;
            ushort4 o;
            o.x = f2b(Wl[(size_t)(kq + 0) * HH + n]);
            o.y = f2b(Wl[(size_t)(kq + 1) * HH + n]);
            o.z = f2b(Wl[(size_t)(kq + 2) * HH + n]);
            o.w = f2b(Wl[(size_t)(kq + 3) * HH + n]);
            *(ushort4*)(Wt + (size_t)l * HH * HH + (size_t)n * HH + kq) = o;
        } else {
            int r = pb - 256;  // 0..102
            int j = threadIdx.x;
            if (r < 100) {
                float acc = bp[j];
                for (int k = 0; k < HH; ++k) acc += atom_emb[r * HH + k] * Wp[(size_t)k * HH + j];
                aref[r * HH + j] = acc;
            } else {
                int tr = r - 100;
                float acc = 0.f;
                for (int k = 0; k < TT; ++k) acc += tag_emb[tr * TT + k] * Wp[(size_t)(HH + k) * HH + j];
                tref[tr * HH + j] = acc;
            }
        }
    }
}

// ---------------- fused MFMA GEMM, 128x256 tile, single A pass ----------------
// hwb[M,256] = bf16( (A @ Wt^T) * dinv[row] )
// mode 0 (layer 0): A[row] = aref[x[row]] + tref[tags[row]]        (h0 fused)
// mode 1 (layers 1+): A[row] = hb_read[row] + relu(bn(aggb[row]))  (epi fused)
// Each block covers all 256 output cols, so A is computed once and written to hb_out.
__global__ __launch_bounds__(512, 2) void k_gemm(
    const unsigned short* __restrict__ hb_read,
    const unsigned short* __restrict__ Wt,
    const float* __restrict__ dinv,
    unsigned short* __restrict__ hwb,
    int mode,
    const int* __restrict__ x, const int* __restrict__ tags,
    const float* __restrict__ aref, const float* __restrict__ tref,
    const unsigned short* __restrict__ aggb,
    const float* __restrict__ colsum, const float* __restrict__ colsq,
    const float* __restrict__ bng, const float* __restrict__ bnb,
    unsigned short* __restrict__ hb_out,
    int M, float invN) {
    __shared__ unsigned short As[128][72];
    __shared__ unsigned short Bs[256][72];
    __shared__ float sc[256], sh[256];
    int t = threadIdx.x;              // 0..511
    int lane = t & 63, w = t >> 6;    // 8 waves
    int wr = w & 1, wc = w >> 1;      // wave covers rows [wr*64,+64), cols [wc*64,+64)
    int l15 = lane & 15, l4 = lane >> 4;
    int row0 = blockIdx.x * 128;

    if (mode == 1 && t < 256) {  // per-column BN scale/shift
        float mu = colsum[t] * invN;
        float var = colsq[t] * invN - mu * mu;
        float s = bng[t] * rsqrtf(var + EPSF);
        sc[t] = s;
        sh[t] = bnb[t] - mu * s;
    }
    __syncthreads();

    float4v acc[4][4];
#pragma unroll
    for (int i = 0; i < 4; ++i)
#pragma unroll
        for (int j = 0; j < 4; ++j) acc[i][j] = (float4v)0.f;

    for (int k0 = 0; k0 < 256; k0 += 64) {
        if (k0) __syncthreads();
        // B tile: 256 n-rows x 64 k
#pragma unroll
        for (int u = 0; u < 4; ++u) {
            int idx = u * 512 + t;          // 0..2047
            int rb = idx >> 3;              // 0..255
            int c = (idx & 7) * 8;
            *(uint4*)&Bs[rb][c] = *(const uint4*)(Wt + (size_t)rb * 256 + k0 + c);
        }
        // A tile: 128 rows x 64 k (computed once per row-block)
#pragma unroll
        for (int u = 0; u < 2; ++u) {
            int idx = u * 512 + t;          // 0..1023
            int r = idx >> 3;               // 0..127
            int c = (idx & 7) * 8;
            int grow = row0 + r;
            int gcol = k0 + c;
            uint4 ov;
            if (grow < M) {
                unsigned o[4];
                if (mode == 0) {
                    const float* ar = aref + (size_t)x[grow] * 256 + gcol;
                    const float* tr = tref + (size_t)tags[grow] * 256 + gcol;
                    float4 a0 = *(const float4*)ar, a1 = *(const float4*)(ar + 4);
                    float4 t0 = *(const float4*)tr, t1 = *(const float4*)(tr + 4);
                    o[0] = pack2(a0.x + t0.x, a0.y + t0.y);
                    o[1] = pack2(a0.z + t0.z, a0.w + t0.w);
                    o[2] = pack2(a1.x + t1.x, a1.y + t1.y);
                    o[3] = pack2(a1.z + t1.z, a1.w + t1.w);
                } else {
                    uint4 hv = *(const uint4*)(hb_read + (size_t)grow * 256 + gcol);
                    uint4 av = *(const uint4*)(aggb + (size_t)grow * 256 + gcol);
                    const unsigned* hvp = (const unsigned*)&hv;
                    const unsigned* avp = (const unsigned*)&av;
#pragma unroll
                    for (int j = 0; j < 4; ++j) {
                        unsigned hj = hvp[j], aj = avp[j];
                        float h0 = __uint_as_float(hj << 16);
                        float h1 = __uint_as_float(hj & 0xFFFF0000u);
                        float a0 = __uint_as_float(aj << 16);
                        float a1 = __uint_as_float(aj & 0xFFFF0000u);
                        int cc = gcol + j * 2;
                        float v0 = fmaxf(a0 * sc[cc] + sh[cc], 0.f);
                        float v1 = fmaxf(a1 * sc[cc + 1] + sh[cc + 1], 0.f);
                        o[j] = pack2(h0 + v0, h1 + v1);
                    }
                }
                ov = make_uint4(o[0], o[1], o[2], o[3]);
                *(uint4*)(hb_out + (size_t)grow * 256 + gcol) = ov;
            } else {
                ov = make_uint4(0u, 0u, 0u, 0u);
            }
            *(uint4*)&As[r][c] = ov;
        }
        __syncthreads();
#pragma unroll
        for (int kk = 0; kk < 64; kk += 32) {
            short8 a[4], b[4];
#pragma unroll
            for (int i = 0; i < 4; ++i)
                a[i] = *(const short8*)&As[wr * 64 + i * 16 + l15][kk + l4 * 8];
#pragma unroll
            for (int i = 0; i < 4; ++i)
                b[i] = *(const short8*)&Bs[wc * 64 + i * 16 + l15][kk + l4 * 8];
#pragma unroll
            for (int mi = 0; mi < 4; ++mi)
#pragma unroll
                for (int ni = 0; ni < 4; ++ni)
                    acc[mi][ni] = __builtin_amdgcn_mfma_f32_16x16x32_bf16(
                        a[mi], b[ni], acc[mi][ni], 0, 0, 0);
        }
    }
    // epilogue: C/D layout col=lane&15, row=(lane>>4)*4+reg
#pragma unroll
    for (int mi = 0; mi < 4; ++mi) {
        int mb = row0 + wr * 64 + mi * 16 + l4 * 4;
        float dv[4];
#pragma unroll
        for (int r = 0; r < 4; ++r) dv[r] = (mb + r < M) ? dinv[mb + r] : 0.f;
#pragma unroll
        for (int ni = 0; ni < 4; ++ni) {
            int n = wc * 64 + ni * 16 + l15;
#pragma unroll
            for (int r = 0; r < 4; ++r) {
                if (mb + r < M)
                    hwb[(size_t)(mb + r) * 256 + n] = f2b(acc[mi][ni][r] * dv[r]);
            }
        }
    }
}

// ---------------- CSR aggregation (bf16 row gathers, 8x unrolled): one wave/node ----------------
__global__ void k_agg(const unsigned short* __restrict__ hwb, unsigned short* __restrict__ aggb,
                      const int* __restrict__ csr, const int* __restrict__ rs,
                      const int* __restrict__ cnt, const float* __restrict__ dinv,
                      const float* __restrict__ bias, int N) {
    int wave = threadIdx.x >> 6;
    int lane = threadIdx.x & 63;
    int n = blockIdx.x * 4 + wave;
    if (n >= N) return;
    float dn = dinv[n];
    int e = rs[n];
    int end = e + cnt[n];
    // self term (hwb already carries dinv[src])
    float4 acc = bf4_to_f4(((const ushort4*)(hwb + (size_t)n * HH))[lane]);
    for (; e + 8 <= end; e += 8) {
        int s0 = csr[e],     s1 = csr[e + 1], s2 = csr[e + 2], s3 = csr[e + 3];
        int s4 = csr[e + 4], s5 = csr[e + 5], s6 = csr[e + 6], s7 = csr[e + 7];
        float4 m0 = bf4_to_f4(((const ushort4*)(hwb + (size_t)s0 * HH))[lane]);
        float4 m1 = bf4_to_f4(((const ushort4*)(hwb + (size_t)s1 * HH))[lane]);
        float4 m2 = bf4_to_f4(((const ushort4*)(hwb + (size_t)s2 * HH))[lane]);
        float4 m3 = bf4_to_f4(((const ushort4*)(hwb + (size_t)s3 * HH))[lane]);
        float4 m4 = bf4_to_f4(((const ushort4*)(hwb + (size_t)s4 * HH))[lane]);
        float4 m5 = bf4_to_f4(((const ushort4*)(hwb + (size_t)s5 * HH))[lane]);
        float4 m6 = bf4_to_f4(((const ushort4*)(hwb + (size_t)s6 * HH))[lane]);
        float4 m7 = bf4_to_f4(((const ushort4*)(hwb + (size_t)s7 * HH))[lane]);
        acc.x += ((m0.x + m1.x) + (m2.x + m3.x)) + ((m4.x + m5.x) + (m6.x + m7.x));
        acc.y += ((m0.y + m1.y) + (m2.y + m3.y)) + ((m4.y + m5.y) + (m6.y + m7.y));
        acc.z += ((m0.z + m1.z) + (m2.z + m3.z)) + ((m4.z + m5.z) + (m6.z + m7.z));
        acc.w += ((m0.w + m1.w) + (m2.w + m3.w)) + ((m4.w + m5.w) + (m6.w + m7.w));
    }
    for (; e + 4 <= end; e += 4) {
        int s0 = csr[e], s1 = csr[e + 1], s2 = csr[e + 2], s3 = csr[e + 3];
        float4 m0 = bf4_to_f4(((const ushort4*)(hwb + (size_t)s0 * HH))[lane]);
        float4 m1 = bf4_to_f4(((const ushort4*)(hwb + (size_t)s1 * HH))[lane]);
        float4 m2 = bf4_to_f4(((const ushort4*)(hwb + (size_t)s2 * HH))[lane]);
        float4 m3 = bf4_to_f4(((const ushort4*)(hwb + (size_t)s3 * HH))[lane]);
        acc.x += (m0.x + m1.x) + (m2.x + m3.x);
        acc.y += (m0.y + m1.y) + (m2.y + m3.y);
        acc.z += (m0.z + m1.z) + (m2.z + m3.z);
        acc.w += (m0.w + m1.w) + (m2.w + m3.w);
    }
    for (; e < end; ++e) {
        int s = csr[e];
        float4 m = bf4_to_f4(((const ushort4*)(hwb + (size_t)s * HH))[lane]);
        acc.x += m.x; acc.y += m.y; acc.z += m.z; acc.w += m.w;
    }
    float4 b = ((const float4*)bias)[lane];
    ushort4 u;
    u.x = f2b(acc.x * dn + b.x); u.y = f2b(acc.y * dn + b.y);
    u.z = f2b(acc.z * dn + b.z); u.w = f2b(acc.w * dn + b.w);
    ((ushort4*)(aggb + (size_t)n * HH))[lane] = u;
}

// ---------------- BN stats (col sum / sumsq) over bf16 agg ----------------
__global__ __launch_bounds__(256) void k_bnstats(const ushort4* __restrict__ aggb,
                                                 float* __restrict__ colsum,
                                                 float* __restrict__ colsq, int N) {
    __shared__ float4 ssum[4][64];
    __shared__ float4 ssq[4][64];
    int lane = threadIdx.x & 63;
    int wv = threadIdx.x >> 6;
    int rows_per = (N + gridDim.x - 1) / gridDim.x;
    int r0 = blockIdx.x * rows_per;
    int r1 = r0 + rows_per; if (r1 > N) r1 = N;
    float4 s = make_float4(0.f, 0.f, 0.f, 0.f);
    float4 s2 = make_float4(0.f, 0.f, 0.f, 0.f);
    for (int r = r0 + wv; r < r1; r += 4) {
        float4 v = bf4_to_f4(aggb[(size_t)r * 64 + lane]);
        s.x += v.x; s.y += v.y; s.z += v.z; s.w += v.w;
        s2.x += v.x * v.x; s2.y += v.y * v.y; s2.z += v.z * v.z; s2.w += v.w * v.w;
    }
    ssum[wv][lane] = s;
    ssq[wv][lane] = s2;
    __syncthreads();
    int j = lane * 4;
    if (wv == 0) {
        float4 a = ssum[0][lane], b = ssum[1][lane], c = ssum[2][lane], d = ssum[3][lane];
        atomicAdd(&colsum[j + 0], a.x + b.x + c.x + d.x);
        atomicAdd(&colsum[j + 1], a.y + b.y + c.y + d.y);
        atomicAdd(&colsum[j + 2], a.z + b.z + c.z + d.z);
        atomicAdd(&colsum[j + 3], a.w + b.w + c.w + d.w);
    } else if (wv == 1) {
        float4 a = ssq[0][lane], b = ssq[1][lane], c = ssq[2][lane], d = ssq[3][lane];
        atomicAdd(&colsq[j + 0], a.x + b.x + c.x + d.x);
        atomicAdd(&colsq[j + 1], a.y + b.y + c.y + d.y);
        atomicAdd(&colsq[j + 2], a.z + b.z + c.z + d.z);
        atomicAdd(&colsq[j + 3], a.w + b.w + c.w + d.w);
    }
}

// ---------------- pool (fused layer-3 epi) + MLP head, one block per graph ----------------
__global__ __launch_bounds__(256) void k_poolhead(
    const unsigned short* __restrict__ hb, const unsigned short* __restrict__ aggb,
    const int* __restrict__ gstart,
    const float* __restrict__ colsum, const float* __restrict__ colsq,
    const float* __restrict__ bng, const float* __restrict__ bnb,
    const float* __restrict__ W1, const float* __restrict__ b1,
    const float* __restrict__ W2, const float* __restrict__ b2,
    float* __restrict__ out, float invN) {
    __shared__ float4 sm[4][64];
    __shared__ float prow[256];
    __shared__ float hred[128];
    int g = blockIdx.x;
    int t = threadIdx.x;
    int lane = t & 63, wv = t >> 6;
    int col = lane * 4;
    float4 cs = *(const float4*)(colsum + col);
    float4 cq = *(const float4*)(colsq + col);
    float4 g4 = *(const float4*)(bng + col);
    float4 b4 = *(const float4*)(bnb + col);
    float4 scl, shf;
    float mu, var;
    mu = cs.x * invN; var = cq.x * invN - mu * mu; scl.x = g4.x * rsqrtf(var + EPSF); shf.x = b4.x - mu * scl.x;
    mu = cs.y * invN; var = cq.y * invN - mu * mu; scl.y = g4.y * rsqrtf(var + EPSF); shf.y = b4.y - mu * scl.y;
    mu = cs.z * invN; var = cq.z * invN - mu * mu; scl.z = g4.z * rsqrtf(var + EPSF); shf.z = b4.z - mu * scl.z;
    mu = cs.w * invN; var = cq.w * invN - mu * mu; scl.w = g4.w * rsqrtf(var + EPSF); shf.w = b4.w - mu * scl.w;
    int s = gstart[g], e = gstart[g + 1];
    float4 acc = make_float4(0.f, 0.f, 0.f, 0.f);
    for (int n = s + wv; n < e; n += 4) {
        float4 hv = bf4_to_f4(((const ushort4*)hb)[(size_t)n * 64 + lane]);
        float4 av = bf4_to_f4(((const ushort4*)aggb)[(size_t)n * 64 + lane]);
        acc.x += hv.x + fmaxf(av.x * scl.x + shf.x, 0.f);
        acc.y += hv.y + fmaxf(av.y * scl.y + shf.y, 0.f);
        acc.z += hv.z + fmaxf(av.z * scl.z + shf.z, 0.f);
        acc.w += hv.w + fmaxf(av.w * scl.w + shf.w, 0.f);
    }
    sm[wv][lane] = acc;
    __syncthreads();
    if (wv == 0) {
        float4 a = sm[0][lane], b = sm[1][lane], c = sm[2][lane], d = sm[3][lane];
        float inv = 1.0f / fmaxf((float)(e - s), 1.0f);
        prow[col + 0] = (a.x + b.x + c.x + d.x) * inv;
        prow[col + 1] = (a.y + b.y + c.y + d.y) * inv;
        prow[col + 2] = (a.z + b.z + c.z + d.z) * inv;
        prow[col + 3] = (a.w + b.w + c.w + d.w) * inv;
    }
    __syncthreads();
    // head
    if (t < 128) {
        float acc1 = b1[t];
        for (int k = 0; k < HH; ++k) acc1 += prow[k] * W1[(size_t)k * 128 + t];
        hred[t] = fmaxf(acc1, 0.f) * W2[t];
    }
    __syncthreads();
    for (int off = 64; off > 0; off >>= 1) {
        if (t < off) hred[t] += hred[t + off];
        __syncthreads();
    }
    if (t == 0) out[g] = hred[0] + b2[0];
}

extern "C" void kernel_launch(void* const* d_in, const int* in_sizes, int n_in,
                              void* d_out, int out_size, void* d_ws, size_t ws_size,
                              hipStream_t stream) {
    const int* x        = (const int*)d_in[0];
    const int* tags     = (const int*)d_in[1];
    const int* ei       = (const int*)d_in[2];
    const int* batch    = (const int*)d_in[3];
    const float* atom_e = (const float*)d_in[4];
    const float* tag_e  = (const float*)d_in[5];
    const float* Wp     = (const float*)d_in[6];
    const float* bp     = (const float*)d_in[7];
    const float* gcn_W  = (const float*)d_in[8];
    const float* gcn_b  = (const float*)d_in[9];
    const float* bn_g   = (const float*)d_in[10];
    const float* bn_b   = (const float*)d_in[11];
    const float* W1     = (const float*)d_in[12];
    const float* b1     = (const float*)d_in[13];
    const float* W2     = (const float*)d_in[14];
    const float* b2     = (const float*)d_in[15];
    float* out = (float*)d_out;

    const int N = NN, E = EE, G = GG, H = HH;
    const int Mpad = ((N + 127) / 128) * 128;  // 50048
    const float invN = 1.0f / (float)N;

    char* p = (char*)d_ws;
    auto alloc = [&](size_t bytes) {
        void* r = (void*)p;
        p += (bytes + 255) & ~(size_t)255;
        return r;
    };
    unsigned short* hbA = (unsigned short*)alloc((size_t)Mpad * H * 2);
    unsigned short* hbB = (unsigned short*)alloc((size_t)Mpad * H * 2);
    unsigned short* hwb = (unsigned short*)alloc((size_t)Mpad * H * 2);
    unsigned short* Wt  = (unsigned short*)alloc((size_t)LL * H * H * 2);
    unsigned short* aggb= (unsigned short*)alloc((size_t)N * H * 2);
    float* dinv = (float*)alloc((size_t)N * 4);
    int* rs     = (int*)alloc((size_t)N * 4);
    int* cur    = (int*)alloc((size_t)N * 4);
    int* csr    = (int*)alloc((size_t)E * 4);
    int* bsum   = (int*)alloc(64 * 4);
    float* aref = (float*)alloc(100 * (size_t)H * 4);
    float* tref = (float*)alloc(3 * (size_t)H * 4);
    int* gstart = (int*)alloc((size_t)(G + 1) * 4);
    // zero-init region: cnt | cstat[4][512] (contiguous allocs, one memset)
    int* cnt    = (int*)alloc((size_t)N * 4);
    float* cstat= (float*)alloc((size_t)LL * 512 * 4);
    size_t zspan = (size_t)((char*)cstat + (size_t)LL * 512 * 4 - (char*)cnt);

    const int* src = ei;
    const int* dst = ei + E;

    hipMemsetAsync(cnt, 0, zspan, stream);

    k_degree<<<(E + 255) / 256, 256, 0, stream>>>(dst, cnt, E);
    int nb = (N + 1023) / 1024;  // 49
    k_scan1<<<nb, 1024, 0, stream>>>(cnt, rs, bsum, N);
    k_scan3<<<(N + 255) / 256, 256, 0, stream>>>(rs, cnt, bsum, cur, dinv, N, nb);
    k_prep<<<3680, 256, 0, stream>>>(src, dst, cur, csr, batch, gstart,
                                     atom_e, tag_e, Wp, bp, gcn_W, aref, tref, Wt);

    // ping-pong residual state: layer0 writes hbA; 1->hbB; 2->hbA; 3->hbB
    unsigned short* hbw[4] = {hbA, hbB, hbA, hbB};
    for (int l = 0; l < LL; ++l) {
        const unsigned short* hr = (l == 0) ? hbA : hbw[l - 1];
        const float* cprev = cstat + (size_t)(l > 0 ? l - 1 : 0) * 512;
        const float* bngp = bn_g + (size_t)(l > 0 ? l - 1 : 0) * H;
        const float* bnbp = bn_b + (size_t)(l > 0 ? l - 1 : 0) * H;
        k_gemm<<<dim3(Mpad / 128), 512, 0, stream>>>(
            hr, Wt + (size_t)l * H * H, dinv, hwb,
            (l == 0) ? 0 : 1, x, tags, aref, tref, aggb,
            cprev, cprev + 256, bngp, bnbp, hbw[l], N, invN);
        k_agg<<<(N + 3) / 4, 256, 0, stream>>>(hwb, aggb, csr, rs, cnt, dinv,
                                               gcn_b + (size_t)l * H, N);
        k_bnstats<<<512, 256, 0, stream>>>((const ushort4*)aggb,
                                           cstat + (size_t)l * 512,
                                           cstat + (size_t)l * 512 + 256, N);
    }

    k_poolhead<<<G, 256, 0, stream>>>(hbw[3], aggb, gstart,
                                      cstat + 3 * 512, cstat + 3 * 512 + 256,
                                      bn_g + 3 * (size_t)H, bn_b + 3 * (size_t)H,
                                      W1, b1, W2, b2, out, invN);
}

// Round 12
// 768.378 us; speedup vs baseline: 1.0583x; 1.0583x over previous
//
#include <hip/hip_runtime.h>
#include <hip/hip_bf16.h>

#define NN 50000
#define EE 800000
#define GG 512
#define HH 256
#define TT 32
#define LL 4
#define EPSF 1e-5f

typedef __attribute__((ext_vector_type(8))) short short8;
typedef __attribute__((ext_vector_type(4))) float float4v;

// ---------- bf16 helpers ----------
__device__ inline unsigned short f2b(float f) {  // RNE
    unsigned u = __float_as_uint(f);
    unsigned r = (u + 0x7FFFu + ((u >> 16) & 1u)) >> 16;
    return (unsigned short)r;
}
__device__ inline unsigned pack2(float lo, float hi) {  // v_cvt_pk_bf16_f32
    __hip_bfloat162 b2 = __float22bfloat162_rn(float2{lo, hi});
    return *reinterpret_cast<unsigned*>(&b2);
}
__device__ inline float4 bf4_to_f4(ushort4 u) {
    float4 f;
    f.x = __uint_as_float((unsigned)u.x << 16);
    f.y = __uint_as_float((unsigned)u.y << 16);
    f.z = __uint_as_float((unsigned)u.z << 16);
    f.w = __uint_as_float((unsigned)u.w << 16);
    return f;
}

// ---------------- degree ----------------
__global__ void k_degree(const int* __restrict__ dst, int* __restrict__ cnt, int E) {
    int e = blockIdx.x * 256 + threadIdx.x;
    if (e < E) atomicAdd(&cnt[dst[e]], 1);
}

// ---------------- scan phase 1: per-1024-chunk inclusive scan ----------------
__global__ void k_scan1(const int* __restrict__ cnt, int* __restrict__ incl,
                        int* __restrict__ bsum, int N) {
    __shared__ int s[1024];
    int i = blockIdx.x * 1024 + threadIdx.x;
    int v = (i < N) ? cnt[i] : 0;
    s[threadIdx.x] = v;
    __syncthreads();
    for (int off = 1; off < 1024; off <<= 1) {
        int t = (threadIdx.x >= off) ? s[threadIdx.x - off] : 0;
        __syncthreads();
        s[threadIdx.x] += t;
        __syncthreads();
    }
    if (i < N) incl[i] = s[threadIdx.x];
    if (threadIdx.x == 1023) bsum[blockIdx.x] = s[1023];
}

// ---------------- scan phase 2 (merged): local bsum scan + offsets + dinv + cur ----------------
__global__ void k_scan3(int* __restrict__ rs, const int* __restrict__ cnt,
                        const int* __restrict__ bsum, int* __restrict__ cur,
                        float* __restrict__ dinv, int N, int nb) {
    __shared__ int sb[64];
    __shared__ int ex[64];
    int t = threadIdx.x;
    if (t < 64) sb[t] = (t < nb) ? bsum[t] : 0;
    __syncthreads();
    for (int off = 1; off < 64; off <<= 1) {
        int v = 0;
        if (t < 64 && t >= off) v = sb[t - off];
        __syncthreads();
        if (t < 64) sb[t] += v;
        __syncthreads();
    }
    if (t < 64) ex[t] = sb[t] - ((t < nb) ? bsum[t] : 0);  // exclusive
    __syncthreads();
    int i = blockIdx.x * 256 + t;
    if (i < N) {
        int c = cnt[i];
        int e = rs[i] + ex[i >> 10] - c;  // exclusive prefix
        rs[i] = e;
        cur[i] = e;
        dinv[i] = rsqrtf((float)c + 1.0f);
    }
}

// ---------------- merged prep: scatter | gbound | projw (independent jobs) ----------------
__global__ void k_prep(const int* __restrict__ src, const int* __restrict__ dst,
                       int* __restrict__ cur, int* __restrict__ csr,
                       const int* __restrict__ batch, int* __restrict__ gstart,
                       const float* __restrict__ atom_emb, const float* __restrict__ tag_emb,
                       const float* __restrict__ Wp, const float* __restrict__ bp,
                       const float* __restrict__ W,
                       float* __restrict__ aref, float* __restrict__ tref,
                       unsigned short* __restrict__ Wt) {
    int blk = blockIdx.x;
    if (blk < 3125) {  // scatter (cur pre-initialized to row starts)
        int e = blk * 256 + threadIdx.x;
        if (e >= EE) return;
        int p = atomicAdd(&cur[dst[e]], 1);
        csr[p] = src[e];
    } else if (blk < 3125 + 196) {  // gbound
        int n = (blk - 3125) * 256 + threadIdx.x;
        if (n >= NN) return;
        int b = batch[n];
        int prev = (n == 0) ? -1 : batch[n - 1];
        for (int g = prev + 1; g <= b; ++g) gstart[g] = n;
        if (n == NN - 1)
            for (int g = b + 1; g <= GG; ++g) gstart[g] = NN;
    } else {
        int pb = blk - 3321;  // 0..358
        if (pb < 256) {  // wprep: Wt[l][n][k] bf16
            int l = pb >> 6;
            int bx = pb & 63;
            int n = bx * 4 + (threadIdx.x >> 6);
            int kq = (threadIdx.x & 63) * 4;
            const float* Wl = W + (size_t)l * HH * HH;
            ushort4 o;
            o.x = f2b(Wl[(size_t)(kq + 0) * HH + n]);
            o.y = f2b(Wl[(size_t)(kq + 1) * HH + n]);
            o.z = f2b(Wl[(size_t)(kq + 2) * HH + n]);
            o.w = f2b(Wl[(size_t)(kq + 3) * HH + n]);
            *(ushort4*)(Wt + (size_t)l * HH * HH + (size_t)n * HH + kq) = o;
        } else {
            int r = pb - 256;  // 0..102
            int j = threadIdx.x;
            if (r < 100) {
                float acc = bp[j];
                for (int k = 0; k < HH; ++k) acc += atom_emb[r * HH + k] * Wp[(size_t)k * HH + j];
                aref[r * HH + j] = acc;
            } else {
                int tr = r - 100;
                float acc = 0.f;
                for (int k = 0; k < TT; ++k) acc += tag_emb[tr * TT + k] * Wp[(size_t)(HH + k) * HH + j];
                tref[tr * HH + j] = acc;
            }
        }
    }
}

// ---------------- fused MFMA GEMM, 128x256 tile, single A pass ----------------
// launch_bounds(512,4): 4 waves/EU min -> 2 blocks/CU -> all 391 blocks co-resident.
__global__ __launch_bounds__(512, 4) void k_gemm(
    const unsigned short* __restrict__ hb_read,
    const unsigned short* __restrict__ Wt,
    const float* __restrict__ dinv,
    unsigned short* __restrict__ hwb,
    int mode,
    const int* __restrict__ x, const int* __restrict__ tags,
    const float* __restrict__ aref, const float* __restrict__ tref,
    const unsigned short* __restrict__ aggb,
    const float* __restrict__ colsum, const float* __restrict__ colsq,
    const float* __restrict__ bng, const float* __restrict__ bnb,
    unsigned short* __restrict__ hb_out,
    int M, float invN) {
    __shared__ unsigned short As[128][72];
    __shared__ unsigned short Bs[256][72];
    __shared__ float sc[256], sh[256];
    int t = threadIdx.x;              // 0..511
    int lane = t & 63, w = t >> 6;    // 8 waves
    int wr = w & 1, wc = w >> 1;      // wave covers rows [wr*64,+64), cols [wc*64,+64)
    int l15 = lane & 15, l4 = lane >> 4;
    int row0 = blockIdx.x * 128;

    if (mode == 1 && t < 256) {  // per-column BN scale/shift
        float mu = colsum[t] * invN;
        float var = colsq[t] * invN - mu * mu;
        float s = bng[t] * rsqrtf(var + EPSF);
        sc[t] = s;
        sh[t] = bnb[t] - mu * s;
    }
    __syncthreads();

    float4v acc[4][4];
#pragma unroll
    for (int i = 0; i < 4; ++i)
#pragma unroll
        for (int j = 0; j < 4; ++j) acc[i][j] = (float4v)0.f;

    for (int k0 = 0; k0 < 256; k0 += 64) {
        if (k0) __syncthreads();
        // B tile: 256 n-rows x 64 k
#pragma unroll
        for (int u = 0; u < 4; ++u) {
            int idx = u * 512 + t;          // 0..2047
            int rb = idx >> 3;              // 0..255
            int c = (idx & 7) * 8;
            *(uint4*)&Bs[rb][c] = *(const uint4*)(Wt + (size_t)rb * 256 + k0 + c);
        }
        // A tile: 128 rows x 64 k (computed once per row-block)
#pragma unroll
        for (int u = 0; u < 2; ++u) {
            int idx = u * 512 + t;          // 0..1023
            int r = idx >> 3;               // 0..127
            int c = (idx & 7) * 8;
            int grow = row0 + r;
            int gcol = k0 + c;
            uint4 ov;
            if (grow < M) {
                unsigned o[4];
                if (mode == 0) {
                    const float* ar = aref + (size_t)x[grow] * 256 + gcol;
                    const float* tr = tref + (size_t)tags[grow] * 256 + gcol;
                    float4 a0 = *(const float4*)ar, a1 = *(const float4*)(ar + 4);
                    float4 t0 = *(const float4*)tr, t1 = *(const float4*)(tr + 4);
                    o[0] = pack2(a0.x + t0.x, a0.y + t0.y);
                    o[1] = pack2(a0.z + t0.z, a0.w + t0.w);
                    o[2] = pack2(a1.x + t1.x, a1.y + t1.y);
                    o[3] = pack2(a1.z + t1.z, a1.w + t1.w);
                } else {
                    uint4 hv = *(const uint4*)(hb_read + (size_t)grow * 256 + gcol);
                    uint4 av = *(const uint4*)(aggb + (size_t)grow * 256 + gcol);
                    const unsigned* hvp = (const unsigned*)&hv;
                    const unsigned* avp = (const unsigned*)&av;
#pragma unroll
                    for (int j = 0; j < 4; ++j) {
                        unsigned hj = hvp[j], aj = avp[j];
                        float h0 = __uint_as_float(hj << 16);
                        float h1 = __uint_as_float(hj & 0xFFFF0000u);
                        float a0 = __uint_as_float(aj << 16);
                        float a1 = __uint_as_float(aj & 0xFFFF0000u);
                        int cc = gcol + j * 2;
                        float v0 = fmaxf(a0 * sc[cc] + sh[cc], 0.f);
                        float v1 = fmaxf(a1 * sc[cc + 1] + sh[cc + 1], 0.f);
                        o[j] = pack2(h0 + v0, h1 + v1);
                    }
                }
                ov = make_uint4(o[0], o[1], o[2], o[3]);
                *(uint4*)(hb_out + (size_t)grow * 256 + gcol) = ov;
            } else {
                ov = make_uint4(0u, 0u, 0u, 0u);
            }
            *(uint4*)&As[r][c] = ov;
        }
        __syncthreads();
#pragma unroll
        for (int kk = 0; kk < 64; kk += 32) {
            short8 a[4], b[4];
#pragma unroll
            for (int i = 0; i < 4; ++i)
                a[i] = *(const short8*)&As[wr * 64 + i * 16 + l15][kk + l4 * 8];
#pragma unroll
            for (int i = 0; i < 4; ++i)
                b[i] = *(const short8*)&Bs[wc * 64 + i * 16 + l15][kk + l4 * 8];
#pragma unroll
            for (int mi = 0; mi < 4; ++mi)
#pragma unroll
                for (int ni = 0; ni < 4; ++ni)
                    acc[mi][ni] = __builtin_amdgcn_mfma_f32_16x16x32_bf16(
                        a[mi], b[ni], acc[mi][ni], 0, 0, 0);
        }
    }
    // epilogue: C/D layout col=lane&15, row=(lane>>4)*4+reg
#pragma unroll
    for (int mi = 0; mi < 4; ++mi) {
        int mb = row0 + wr * 64 + mi * 16 + l4 * 4;
        float dv[4];
#pragma unroll
        for (int r = 0; r < 4; ++r) dv[r] = (mb + r < M) ? dinv[mb + r] : 0.f;
#pragma unroll
        for (int ni = 0; ni < 4; ++ni) {
            int n = wc * 64 + ni * 16 + l15;
#pragma unroll
            for (int r = 0; r < 4; ++r) {
                if (mb + r < M)
                    hwb[(size_t)(mb + r) * 256 + n] = f2b(acc[mi][ni][r] * dv[r]);
            }
        }
    }
}

// ---------------- CSR aggregation (bf16 row gathers, 8x unrolled): one wave/node ----------------
__global__ void k_agg(const unsigned short* __restrict__ hwb, unsigned short* __restrict__ aggb,
                      const int* __restrict__ csr, const int* __restrict__ rs,
                      const int* __restrict__ cnt, const float* __restrict__ dinv,
                      const float* __restrict__ bias, int N) {
    int wave = threadIdx.x >> 6;
    int lane = threadIdx.x & 63;
    int n = blockIdx.x * 4 + wave;
    if (n >= N) return;
    float dn = dinv[n];
    int e = rs[n];
    int end = e + cnt[n];
    // self term (hwb already carries dinv[src])
    float4 acc = bf4_to_f4(((const ushort4*)(hwb + (size_t)n * HH))[lane]);
    for (; e + 8 <= end; e += 8) {
        int s0 = csr[e],     s1 = csr[e + 1], s2 = csr[e + 2], s3 = csr[e + 3];
        int s4 = csr[e + 4], s5 = csr[e + 5], s6 = csr[e + 6], s7 = csr[e + 7];
        float4 m0 = bf4_to_f4(((const ushort4*)(hwb + (size_t)s0 * HH))[lane]);
        float4 m1 = bf4_to_f4(((const ushort4*)(hwb + (size_t)s1 * HH))[lane]);
        float4 m2 = bf4_to_f4(((const ushort4*)(hwb + (size_t)s2 * HH))[lane]);
        float4 m3 = bf4_to_f4(((const ushort4*)(hwb + (size_t)s3 * HH))[lane]);
        float4 m4 = bf4_to_f4(((const ushort4*)(hwb + (size_t)s4 * HH))[lane]);
        float4 m5 = bf4_to_f4(((const ushort4*)(hwb + (size_t)s5 * HH))[lane]);
        float4 m6 = bf4_to_f4(((const ushort4*)(hwb + (size_t)s6 * HH))[lane]);
        float4 m7 = bf4_to_f4(((const ushort4*)(hwb + (size_t)s7 * HH))[lane]);
        acc.x += ((m0.x + m1.x) + (m2.x + m3.x)) + ((m4.x + m5.x) + (m6.x + m7.x));
        acc.y += ((m0.y + m1.y) + (m2.y + m3.y)) + ((m4.y + m5.y) + (m6.y + m7.y));
        acc.z += ((m0.z + m1.z) + (m2.z + m3.z)) + ((m4.z + m5.z) + (m6.z + m7.z));
        acc.w += ((m0.w + m1.w) + (m2.w + m3.w)) + ((m4.w + m5.w) + (m6.w + m7.w));
    }
    for (; e + 4 <= end; e += 4) {
        int s0 = csr[e], s1 = csr[e + 1], s2 = csr[e + 2], s3 = csr[e + 3];
        float4 m0 = bf4_to_f4(((const ushort4*)(hwb + (size_t)s0 * HH))[lane]);
        float4 m1 = bf4_to_f4(((const ushort4*)(hwb + (size_t)s1 * HH))[lane]);
        float4 m2 = bf4_to_f4(((const ushort4*)(hwb + (size_t)s2 * HH))[lane]);
        float4 m3 = bf4_to_f4(((const ushort4*)(hwb + (size_t)s3 * HH))[lane]);
        acc.x += (m0.x + m1.x) + (m2.x + m3.x);
        acc.y += (m0.y + m1.y) + (m2.y + m3.y);
        acc.z += (m0.z + m1.z) + (m2.z + m3.z);
        acc.w += (m0.w + m1.w) + (m2.w + m3.w);
    }
    for (; e < end; ++e) {
        int s = csr[e];
        float4 m = bf4_to_f4(((const ushort4*)(hwb + (size_t)s * HH))[lane]);
        acc.x += m.x; acc.y += m.y; acc.z += m.z; acc.w += m.w;
    }
    float4 b = ((const float4*)bias)[lane];
    ushort4 u;
    u.x = f2b(acc.x * dn + b.x); u.y = f2b(acc.y * dn + b.y);
    u.z = f2b(acc.z * dn + b.z); u.w = f2b(acc.w * dn + b.w);
    ((ushort4*)(aggb + (size_t)n * HH))[lane] = u;
}

// ---------------- BN stats (col sum / sumsq) over bf16 agg ----------------
__global__ __launch_bounds__(256) void k_bnstats(const ushort4* __restrict__ aggb,
                                                 float* __restrict__ colsum,
                                                 float* __restrict__ colsq, int N) {
    __shared__ float4 ssum[4][64];
    __shared__ float4 ssq[4][64];
    int lane = threadIdx.x & 63;
    int wv = threadIdx.x >> 6;
    int rows_per = (N + gridDim.x - 1) / gridDim.x;
    int r0 = blockIdx.x * rows_per;
    int r1 = r0 + rows_per; if (r1 > N) r1 = N;
    float4 s = make_float4(0.f, 0.f, 0.f, 0.f);
    float4 s2 = make_float4(0.f, 0.f, 0.f, 0.f);
    for (int r = r0 + wv; r < r1; r += 4) {
        float4 v = bf4_to_f4(aggb[(size_t)r * 64 + lane]);
        s.x += v.x; s.y += v.y; s.z += v.z; s.w += v.w;
        s2.x += v.x * v.x; s2.y += v.y * v.y; s2.z += v.z * v.z; s2.w += v.w * v.w;
    }
    ssum[wv][lane] = s;
    ssq[wv][lane] = s2;
    __syncthreads();
    int j = lane * 4;
    if (wv == 0) {
        float4 a = ssum[0][lane], b = ssum[1][lane], c = ssum[2][lane], d = ssum[3][lane];
        atomicAdd(&colsum[j + 0], a.x + b.x + c.x + d.x);
        atomicAdd(&colsum[j + 1], a.y + b.y + c.y + d.y);
        atomicAdd(&colsum[j + 2], a.z + b.z + c.z + d.z);
        atomicAdd(&colsum[j + 3], a.w + b.w + c.w + d.w);
    } else if (wv == 1) {
        float4 a = ssq[0][lane], b = ssq[1][lane], c = ssq[2][lane], d = ssq[3][lane];
        atomicAdd(&colsq[j + 0], a.x + b.x + c.x + d.x);
        atomicAdd(&colsq[j + 1], a.y + b.y + c.y + d.y);
        atomicAdd(&colsq[j + 2], a.z + b.z + c.z + d.z);
        atomicAdd(&colsq[j + 3], a.w + b.w + c.w + d.w);
    }
}

// ---------------- pool (fused layer-3 epi) + MLP head, one block per graph ----------------
__global__ __launch_bounds__(256) void k_poolhead(
    const unsigned short* __restrict__ hb, const unsigned short* __restrict__ aggb,
    const int* __restrict__ gstart,
    const float* __restrict__ colsum, const float* __restrict__ colsq,
    const float* __restrict__ bng, const float* __restrict__ bnb,
    const float* __restrict__ W1, const float* __restrict__ b1,
    const float* __restrict__ W2, const float* __restrict__ b2,
    float* __restrict__ out, float invN) {
    __shared__ float4 sm[4][64];
    __shared__ float prow[256];
    __shared__ float hred[128];
    int g = blockIdx.x;
    int t = threadIdx.x;
    int lane = t & 63, wv = t >> 6;
    int col = lane * 4;
    float4 cs = *(const float4*)(colsum + col);
    float4 cq = *(const float4*)(colsq + col);
    float4 g4 = *(const float4*)(bng + col);
    float4 b4 = *(const float4*)(bnb + col);
    float4 scl, shf;
    float mu, var;
    mu = cs.x * invN; var = cq.x * invN - mu * mu; scl.x = g4.x * rsqrtf(var + EPSF); shf.x = b4.x - mu * scl.x;
    mu = cs.y * invN; var = cq.y * invN - mu * mu; scl.y = g4.y * rsqrtf(var + EPSF); shf.y = b4.y - mu * scl.y;
    mu = cs.z * invN; var = cq.z * invN - mu * mu; scl.z = g4.z * rsqrtf(var + EPSF); shf.z = b4.z - mu * scl.z;
    mu = cs.w * invN; var = cq.w * invN - mu * mu; scl.w = g4.w * rsqrtf(var + EPSF); shf.w = b4.w - mu * scl.w;
    int s = gstart[g], e = gstart[g + 1];
    float4 acc = make_float4(0.f, 0.f, 0.f, 0.f);
    for (int n = s + wv; n < e; n += 4) {
        float4 hv = bf4_to_f4(((const ushort4*)hb)[(size_t)n * 64 + lane]);
        float4 av = bf4_to_f4(((const ushort4*)aggb)[(size_t)n * 64 + lane]);
        acc.x += hv.x + fmaxf(av.x * scl.x + shf.x, 0.f);
        acc.y += hv.y + fmaxf(av.y * scl.y + shf.y, 0.f);
        acc.z += hv.z + fmaxf(av.z * scl.z + shf.z, 0.f);
        acc.w += hv.w + fmaxf(av.w * scl.w + shf.w, 0.f);
    }
    sm[wv][lane] = acc;
    __syncthreads();
    if (wv == 0) {
        float4 a = sm[0][lane], b = sm[1][lane], c = sm[2][lane], d = sm[3][lane];
        float inv = 1.0f / fmaxf((float)(e - s), 1.0f);
        prow[col + 0] = (a.x + b.x + c.x + d.x) * inv;
        prow[col + 1] = (a.y + b.y + c.y + d.y) * inv;
        prow[col + 2] = (a.z + b.z + c.z + d.z) * inv;
        prow[col + 3] = (a.w + b.w + c.w + d.w) * inv;
    }
    __syncthreads();
    // head
    if (t < 128) {
        float acc1 = b1[t];
        for (int k = 0; k < HH; ++k) acc1 += prow[k] * W1[(size_t)k * 128 + t];
        hred[t] = fmaxf(acc1, 0.f) * W2[t];
    }
    __syncthreads();
    for (int off = 64; off > 0; off >>= 1) {
        if (t < off) hred[t] += hred[t + off];
        __syncthreads();
    }
    if (t == 0) out[g] = hred[0] + b2[0];
}

extern "C" void kernel_launch(void* const* d_in, const int* in_sizes, int n_in,
                              void* d_out, int out_size, void* d_ws, size_t ws_size,
                              hipStream_t stream) {
    const int* x        = (const int*)d_in[0];
    const int* tags     = (const int*)d_in[1];
    const int* ei       = (const int*)d_in[2];
    const int* batch    = (const int*)d_in[3];
    const float* atom_e = (const float*)d_in[4];
    const float* tag_e  = (const float*)d_in[5];
    const float* Wp     = (const float*)d_in[6];
    const float* bp     = (const float*)d_in[7];
    const float* gcn_W  = (const float*)d_in[8];
    const float* gcn_b  = (const float*)d_in[9];
    const float* bn_g   = (const float*)d_in[10];
    const float* bn_b   = (const float*)d_in[11];
    const float* W1     = (const float*)d_in[12];
    const float* b1     = (const float*)d_in[13];
    const float* W2     = (const float*)d_in[14];
    const float* b2     = (const float*)d_in[15];
    float* out = (float*)d_out;

    const int N = NN, E = EE, G = GG, H = HH;
    const int Mpad = ((N + 127) / 128) * 128;  // 50048
    const float invN = 1.0f / (float)N;

    char* p = (char*)d_ws;
    auto alloc = [&](size_t bytes) {
        void* r = (void*)p;
        p += (bytes + 255) & ~(size_t)255;
        return r;
    };
    unsigned short* hbA = (unsigned short*)alloc((size_t)Mpad * H * 2);
    unsigned short* hbB = (unsigned short*)alloc((size_t)Mpad * H * 2);
    unsigned short* hwb = (unsigned short*)alloc((size_t)Mpad * H * 2);
    unsigned short* Wt  = (unsigned short*)alloc((size_t)LL * H * H * 2);
    unsigned short* aggb= (unsigned short*)alloc((size_t)N * H * 2);
    float* dinv = (float*)alloc((size_t)N * 4);
    int* rs     = (int*)alloc((size_t)N * 4);
    int* cur    = (int*)alloc((size_t)N * 4);
    int* csr    = (int*)alloc((size_t)E * 4);
    int* bsum   = (int*)alloc(64 * 4);
    float* aref = (float*)alloc(100 * (size_t)H * 4);
    float* tref = (float*)alloc(3 * (size_t)H * 4);
    int* gstart = (int*)alloc((size_t)(G + 1) * 4);
    // zero-init region: cnt | cstat[4][512] (contiguous allocs, one memset)
    int* cnt    = (int*)alloc((size_t)N * 4);
    float* cstat= (float*)alloc((size_t)LL * 512 * 4);
    size_t zspan = (size_t)((char*)cstat + (size_t)LL * 512 * 4 - (char*)cnt);

    const int* src = ei;
    const int* dst = ei + E;

    hipMemsetAsync(cnt, 0, zspan, stream);

    k_degree<<<(E + 255) / 256, 256, 0, stream>>>(dst, cnt, E);
    int nb = (N + 1023) / 1024;  // 49
    k_scan1<<<nb, 1024, 0, stream>>>(cnt, rs, bsum, N);
    k_scan3<<<(N + 255) / 256, 256, 0, stream>>>(rs, cnt, bsum, cur, dinv, N, nb);
    k_prep<<<3680, 256, 0, stream>>>(src, dst, cur, csr, batch, gstart,
                                     atom_e, tag_e, Wp, bp, gcn_W, aref, tref, Wt);

    // ping-pong residual state: layer0 writes hbA; 1->hbB; 2->hbA; 3->hbB
    unsigned short* hbw[4] = {hbA, hbB, hbA, hbB};
    for (int l = 0; l < LL; ++l) {
        const unsigned short* hr = (l == 0) ? hbA : hbw[l - 1];
        const float* cprev = cstat + (size_t)(l > 0 ? l - 1 : 0) * 512;
        const float* bngp = bn_g + (size_t)(l > 0 ? l - 1 : 0) * H;
        const float* bnbp = bn_b + (size_t)(l > 0 ? l - 1 : 0) * H;
        k_gemm<<<dim3(Mpad / 128), 512, 0, stream>>>(
            hr, Wt + (size_t)l * H * H, dinv, hwb,
            (l == 0) ? 0 : 1, x, tags, aref, tref, aggb,
            cprev, cprev + 256, bngp, bnbp, hbw[l], N, invN);
        k_agg<<<(N + 3) / 4, 256, 0, stream>>>(hwb, aggb, csr, rs, cnt, dinv,
                                               gcn_b + (size_t)l * H, N);
        k_bnstats<<<512, 256, 0, stream>>>((const ushort4*)aggb,
                                           cstat + (size_t)l * 512,
                                           cstat + (size_t)l * 512 + 256, N);
    }

    k_poolhead<<<G, 256, 0, stream>>>(hbw[3], aggb, gstart,
                                      cstat + 3 * 512, cstat + 3 * 512 + 256,
                                      bn_g + 3 * (size_t)H, bn_b + 3 * (size_t)H,
                                      W1, b1, W2, b2, out, invN);
}